// Round 8
// baseline (1384.882 us; speedup 1.0000x reference)
//
#include <hip/hip_runtime.h>
#include <hip/hip_bf16.h>
#include <hip/hip_fp16.h>
#include <hip/hip_cooperative_groups.h>
#include <math.h>

namespace cg = cooperative_groups;

#define NFEAT 128
#define NCLASS 40
#define NCU 256  // MI355X

typedef __attribute__((ext_vector_type(8))) short frag_ab;   // 8 bf16 (4 VGPRs)
typedef __attribute__((ext_vector_type(4))) float frag_cd;   // 4 fp32 acc

static __device__ inline unsigned short f2bf_rne(float f) {
    union { float f; unsigned u; } v;
    v.f = f;
    unsigned r = v.u + 0x7FFFu + ((v.u >> 16) & 1u);
    return (unsigned short)(r >> 16);
}
static __device__ inline float bf2f(unsigned short h) {
    union { unsigned u; float f; } v;
    v.u = ((unsigned)h) << 16;
    return v.f;
}

// ---------------- prep: conv(x->fp16) + zero(cnt) + wprep, by block range ----------------

__global__ __launch_bounds__(256) void prep_kernel(const float* __restrict__ x,
                                                   __half* __restrict__ xh, int xc4,
                                                   int* __restrict__ cnt, int n_nodes,
                                                   const float* __restrict__ W0,
                                                   const float* __restrict__ W1,
                                                   const float* __restrict__ W2,
                                                   const float* __restrict__ W3,
                                                   short* __restrict__ whi,
                                                   short* __restrict__ wlo,
                                                   int convB, int zeroB) {
    int b = blockIdx.x;
    if (b < convB) {
        int i = b * 256 + threadIdx.x;
        if (i < xc4) {
            float4 v = ((const float4*)x)[i];
            ((__half2*)xh)[i * 2 + 0] = __floats2half2_rn(v.x, v.y);
            ((__half2*)xh)[i * 2 + 1] = __floats2half2_rn(v.z, v.w);
        }
    } else if (b < convB + zeroB) {
        int i = (b - convB) * 256 + threadIdx.x;
        if (i < n_nodes) cnt[i] = 0;
    } else {
        int wb = b - convB - zeroB;        // 0..31
        int layer = wb >> 3;               // 8 blocks per layer
        const float* W = layer == 0 ? W0 : layer == 1 ? W1 : layer == 2 ? W2 : W3;
        short* h = whi + (size_t)layer * 16384;
        short* l = wlo + (size_t)layer * 16384;
        int idx = (wb & 7) * 256 + threadIdx.x;  // frag slot 0..2047
        int lane = idx & 63;
        int t = (idx >> 6) & 7;
        int s = idx >> 9;
        int quad = lane >> 4;
        int n = lane & 15;
        int kbase = s * 32 + quad * 8;
        int col = t * 16 + n;
#pragma unroll
        for (int j = 0; j < 8; ++j) {
            float f = W[(size_t)(kbase + j) * NFEAT + col];
            unsigned short hb = f2bf_rne(f);
            unsigned short lb = f2bf_rne(f - bf2f(hb));
            h[(size_t)idx * 8 + j] = (short)hb;
            l[(size_t)idx * 8 + j] = (short)lb;
        }
    }
}

// ---------------- mega: CSR build + 4 fused layers + classifier (cooperative) ----------------

struct MegaP {
    const int* src;
    const int* dst;
    int n_edges;
    int n_nodes;
    int nbt;            // scan tiles = ceil(n_nodes/256), <= 256
    int* cnt;
    int* row_ptr;       // n_nodes+1
    int* woff;
    int* bsums;         // nbt+1
    int* src_sorted;
    __half* xh;         // fp16 feature ping buffer
    float* agg;         // fp32 aggregate buffer
    const short* whi;   // 4 layers of B-frag hi
    const short* wlo;
    const float* b1; const float* b2; const float* b3; const float* b4;
    float* x4;          // final fp32 features (in d_out)
    const float* Wl;
    const float* bl;
    float* logits;
    float* probs;
};

__global__ __launch_bounds__(256, 4) void mega_kernel(MegaP p) {
    cg::grid_group grid = cg::this_grid();
    __shared__ int sd[256];
    const int tid = threadIdx.x;
    const int gid = blockIdx.x * 256 + tid;
    const int gsz = gridDim.x * 256;
    const int n = p.n_nodes;

    // ---- phase 1: hist ----
    {
        int n4 = p.n_edges >> 2;
        for (int i = gid; i < n4; i += gsz) {
            int4 d = ((const int4*)p.dst)[i];
            atomicAdd(&p.cnt[d.x], 1);
            atomicAdd(&p.cnt[d.y], 1);
            atomicAdd(&p.cnt[d.z], 1);
            atomicAdd(&p.cnt[d.w], 1);
        }
        if (gid == 0) {
            for (int e = n4 << 2; e < p.n_edges; ++e) atomicAdd(&p.cnt[p.dst[e]], 1);
        }
    }
    grid.sync();

    // ---- phase 2: scan1 (per-256-tile exclusive scan; excl temp in row_ptr) ----
    for (int t = blockIdx.x; t < p.nbt; t += gridDim.x) {
        int i = t * 256 + tid;
        int v = (i < n) ? p.cnt[i] : 0;
        sd[tid] = v;
        __syncthreads();
#pragma unroll
        for (int off = 1; off < 256; off <<= 1) {
            int tmp = (tid >= off) ? sd[tid - off] : 0;
            __syncthreads();
            sd[tid] += tmp;
            __syncthreads();
        }
        if (i < n) p.row_ptr[i] = sd[tid] - v;
        if (tid == 255) p.bsums[t] = sd[255];
        __syncthreads();
    }
    grid.sync();

    // ---- phase 3: scan2 (block 0 scans block sums; nbt <= 256) ----
    if (blockIdx.x == 0) {
        int v = (tid < p.nbt) ? p.bsums[tid] : 0;
        sd[tid] = v;
        __syncthreads();
#pragma unroll
        for (int off = 1; off < 256; off <<= 1) {
            int tmp = (tid >= off) ? sd[tid - off] : 0;
            __syncthreads();
            sd[tid] += tmp;
            __syncthreads();
        }
        if (tid < p.nbt) p.bsums[tid] = sd[tid] - v;
        if (tid == 255) p.bsums[p.nbt] = sd[255];
    }
    grid.sync();

    // ---- phase 4: scan3 (add block offsets -> row_ptr, woff) ----
    for (int t = blockIdx.x; t < p.nbt; t += gridDim.x) {
        int i = t * 256 + tid;
        if (i < n) {
            int v = p.row_ptr[i] + p.bsums[t];
            p.row_ptr[i] = v;
            p.woff[i] = v;
        }
    }
    if (gid == 0) p.row_ptr[n] = p.bsums[p.nbt];
    grid.sync();

    // ---- phase 5: scatter ----
    {
        int n4 = p.n_edges >> 2;
        for (int i = gid; i < n4; i += gsz) {
            int4 d = ((const int4*)p.dst)[i];
            int4 s = ((const int4*)p.src)[i];
            int p0 = atomicAdd(&p.woff[d.x], 1);
            int p1 = atomicAdd(&p.woff[d.y], 1);
            int p2 = atomicAdd(&p.woff[d.z], 1);
            int p3 = atomicAdd(&p.woff[d.w], 1);
            p.src_sorted[p0] = s.x;
            p.src_sorted[p1] = s.y;
            p.src_sorted[p2] = s.z;
            p.src_sorted[p3] = s.w;
        }
        if (gid == 0) {
            for (int e = n4 << 2; e < p.n_edges; ++e) {
                int q = atomicAdd(&p.woff[p.dst[e]], 1);
                p.src_sorted[q] = p.src[e];
            }
        }
    }
    grid.sync();

    // ---- phases 6..13: 4 x (agg -> gemm) ----
    const int NTa = (n + 15) >> 4;
    const int NTg = (n + 63) >> 6;
    for (int l = 0; l < 4; ++l) {
        // agg: gather fp16 rows -> fp32 agg. Quarter-wave (16 lanes x 16B) per node.
        for (int tg = blockIdx.x; tg < NTa; tg += gridDim.x) {
            int node = tg * 16 + (tid >> 4);
            if (node < n) {
                int c = tid & 15;
                int jb = p.row_ptr[node], je = p.row_ptr[node + 1];
                const uint4* xp = (const uint4*)p.xh;
                float a[8];
#pragma unroll
                for (int i = 0; i < 8; ++i) a[i] = 0.f;
                int j = jb;
                for (; j + 3 < je; j += 4) {
                    int s0 = p.src_sorted[j];
                    int s1 = p.src_sorted[j + 1];
                    int s2 = p.src_sorted[j + 2];
                    int s3 = p.src_sorted[j + 3];
                    uint4 r0 = xp[s0 * 16 + c];
                    uint4 r1 = xp[s1 * 16 + c];
                    uint4 r2 = xp[s2 * 16 + c];
                    uint4 r3 = xp[s3 * 16 + c];
#pragma unroll
                    for (int q = 0; q < 4; ++q) {
                        unsigned u0 = (&r0.x)[q], u1 = (&r1.x)[q], u2 = (&r2.x)[q], u3 = (&r3.x)[q];
                        float2 f0 = __half22float2(*(__half2*)&u0);
                        float2 f1 = __half22float2(*(__half2*)&u1);
                        float2 f2 = __half22float2(*(__half2*)&u2);
                        float2 f3 = __half22float2(*(__half2*)&u3);
                        a[q * 2 + 0] += f0.x + f1.x + f2.x + f3.x;
                        a[q * 2 + 1] += f0.y + f1.y + f2.y + f3.y;
                    }
                }
                for (; j < je; ++j) {
                    int s0 = p.src_sorted[j];
                    uint4 r0 = xp[s0 * 16 + c];
#pragma unroll
                    for (int q = 0; q < 4; ++q) {
                        unsigned u0 = (&r0.x)[q];
                        float2 f0 = __half22float2(*(__half2*)&u0);
                        a[q * 2 + 0] += f0.x;
                        a[q * 2 + 1] += f0.y;
                    }
                }
                float4* op = (float4*)p.agg + (size_t)node * 32 + c * 2;
                op[0] = make_float4(a[0], a[1], a[2], a[3]);
                op[1] = make_float4(a[4], a[5], a[6], a[7]);
            }
        }
        grid.sync();

        // gemm: split-bf16 MFMA (hi*hi + hi*lo + lo*hi), bias+norm+relu epilogue.
        {
            const float* bias = l == 0 ? p.b1 : l == 1 ? p.b2 : l == 2 ? p.b3 : p.b4;
            const frag_ab* WH = (const frag_ab*)(p.whi + (size_t)l * 16384);
            const frag_ab* WL = (const frag_ab*)(p.wlo + (size_t)l * 16384);
            int wave = tid >> 6;
            int lane = tid & 63;
            int quad = lane >> 4;
            int n16 = lane & 15;
            for (int tg = blockIdx.x; tg < NTg; tg += gridDim.x) {
                int base = tg * 64;
                int arow = base + wave * 16 + n16;
                int arc = arow < n ? arow : n - 1;
                const float* Ar = p.agg + (size_t)arc * NFEAT;

                frag_cd acc[8];
#pragma unroll
                for (int t = 0; t < 8; ++t) acc[t] = (frag_cd){0.f, 0.f, 0.f, 0.f};

#pragma unroll
                for (int s = 0; s < 4; ++s) {
                    const float* ap = Ar + s * 32 + quad * 8;
                    float4 x0 = *(const float4*)ap;
                    float4 x1 = *(const float4*)(ap + 4);
                    float xs[8] = {x0.x, x0.y, x0.z, x0.w, x1.x, x1.y, x1.z, x1.w};
                    frag_ab ah, al;
#pragma unroll
                    for (int j = 0; j < 8; ++j) {
                        unsigned short hb = f2bf_rne(xs[j]);
                        ah[j] = (short)hb;
                        al[j] = (short)f2bf_rne(xs[j] - bf2f(hb));
                    }
#pragma unroll
                    for (int t = 0; t < 8; ++t) {
                        frag_ab bh = WH[(s * 8 + t) * 64 + lane];
                        frag_ab bl = WL[(s * 8 + t) * 64 + lane];
                        acc[t] = __builtin_amdgcn_mfma_f32_16x16x32_bf16(ah, bh, acc[t], 0, 0, 0);
                        acc[t] = __builtin_amdgcn_mfma_f32_16x16x32_bf16(ah, bl, acc[t], 0, 0, 0);
                        acc[t] = __builtin_amdgcn_mfma_f32_16x16x32_bf16(al, bh, acc[t], 0, 0, 0);
                    }
                }

                float ssq[4] = {0.f, 0.f, 0.f, 0.f};
#pragma unroll
                for (int t = 0; t < 8; ++t) {
                    float bv = bias[t * 16 + n16];
#pragma unroll
                    for (int r = 0; r < 4; ++r) {
                        acc[t][r] += bv;
                        ssq[r] += acc[t][r] * acc[t][r];
                    }
                }
#pragma unroll
                for (int mask = 1; mask <= 8; mask <<= 1) {
#pragma unroll
                    for (int r = 0; r < 4; ++r) ssq[r] += __shfl_xor(ssq[r], mask);
                }
                float inv[4];
#pragma unroll
                for (int r = 0; r < 4; ++r) inv[r] = 1.0f / fmaxf(sqrtf(ssq[r]), 1e-12f);

                int orow0 = base + wave * 16 + quad * 4;
#pragma unroll
                for (int r = 0; r < 4; ++r) {
                    int orow = orow0 + r;
                    if (orow < n) {
                        if (l < 3) {
                            __half* op = p.xh + (size_t)orow * NFEAT + n16;
#pragma unroll
                            for (int t = 0; t < 8; ++t)
                                op[t * 16] = __float2half(fmaxf(acc[t][r] * inv[r], 0.f));
                        } else {
                            float* op = p.x4 + (size_t)orow * NFEAT + n16;
#pragma unroll
                            for (int t = 0; t < 8; ++t)
                                op[t * 16] = fmaxf(acc[t][r] * inv[r], 0.f);
                        }
                    }
                }
            }
        }
        grid.sync();
    }

    // ---- phase 14: classifier + softmax (store logits first -> lower reg peak) ----
    for (int node = gid; node < n; node += gsz) {
        const float* row = p.x4 + (size_t)node * NFEAT;
        float acc[NCLASS];
#pragma unroll
        for (int c = 0; c < NCLASS; ++c) acc[c] = p.bl[c];
        for (int k = 0; k < NFEAT; k += 4) {
            float4 a = *(const float4*)(row + k);
#pragma unroll
            for (int kk = 0; kk < 4; ++kk) {
                float av = (&a.x)[kk];
                const float* Wr = p.Wl + (k + kk) * NCLASS;
#pragma unroll
                for (int c = 0; c < NCLASS; ++c) acc[c] += av * Wr[c];
            }
        }
        float4* lo = (float4*)(p.logits + (size_t)node * NCLASS);
#pragma unroll
        for (int c = 0; c < NCLASS; c += 4)
            lo[c >> 2] = make_float4(acc[c], acc[c + 1], acc[c + 2], acc[c + 3]);

        float m = acc[0];
#pragma unroll
        for (int c = 1; c < NCLASS; ++c) m = fmaxf(m, acc[c]);
        float sum = 0.f;
#pragma unroll
        for (int c = 0; c < NCLASS; ++c) {
            acc[c] = __expf(acc[c] - m);
            sum += acc[c];
        }
        float is = 1.0f / sum;
        float4* po = (float4*)(p.probs + (size_t)node * NCLASS);
#pragma unroll
        for (int c = 0; c < NCLASS; c += 4)
            po[c >> 2] = make_float4(acc[c] * is, acc[c + 1] * is, acc[c + 2] * is, acc[c + 3] * is);
    }
}

// ---------------- launch ----------------

extern "C" void kernel_launch(void* const* d_in, const int* in_sizes, int n_in,
                              void* d_out, int out_size, void* d_ws, size_t ws_size,
                              hipStream_t stream) {
    const float* x  = (const float*)d_in[0];
    const int*   ei = (const int*)d_in[1];
    const float* W1 = (const float*)d_in[2];
    const float* b1 = (const float*)d_in[3];
    const float* W2 = (const float*)d_in[4];
    const float* b2 = (const float*)d_in[5];
    const float* W3 = (const float*)d_in[6];
    const float* b3 = (const float*)d_in[7];
    const float* W4 = (const float*)d_in[8];
    const float* b4 = (const float*)d_in[9];
    const float* Wl = (const float*)d_in[10];
    const float* bl = (const float*)d_in[11];

    const int n_nodes = in_sizes[0] / NFEAT;  // 50000
    const int n_edges = in_sizes[1] / 2;      // 640000
    const int* src = ei;
    const int* dst = ei + n_edges;

    float* out    = (float*)d_out;
    float* logits = out;
    float* probs  = out + (size_t)n_nodes * NCLASS;
    float* x4     = out + 2 * (size_t)n_nodes * NCLASS;

    char* ws = (char*)d_ws;
    size_t off = 0;
    auto wsalloc = [&](size_t bytes) -> void* {
        void* p = ws + off;
        off += (bytes + 255) & ~(size_t)255;
        return p;
    };
    float*  agg        = (float*)wsalloc((size_t)n_nodes * NFEAT * sizeof(float));
    __half* xh         = (__half*)wsalloc((size_t)n_nodes * NFEAT * sizeof(__half));
    int*    row_ptr    = (int*)wsalloc(((size_t)n_nodes + 1) * sizeof(int));
    int*    woff       = (int*)wsalloc((size_t)n_nodes * sizeof(int));
    int*    cnt        = (int*)wsalloc((size_t)n_nodes * sizeof(int));
    int*    src_sorted = (int*)wsalloc((size_t)n_edges * sizeof(int));
    int     nbt        = (n_nodes + 255) / 256;
    int*    bsums      = (int*)wsalloc(((size_t)nbt + 1) * sizeof(int));
    short*  whi        = (short*)wsalloc((size_t)4 * 16384 * sizeof(short));
    short*  wlo        = (short*)wsalloc((size_t)4 * 16384 * sizeof(short));

    // ---- dispatch 1: prep (conv + zero + wprep) ----
    int xc4   = (n_nodes * NFEAT) / 4;
    int convB = (xc4 + 255) / 256;
    int zeroB = (n_nodes + 255) / 256;
    prep_kernel<<<convB + zeroB + 32, 256, 0, stream>>>(x, xh, xc4, cnt, n_nodes,
                                                        W1, W2, W3, W4, whi, wlo,
                                                        convB, zeroB);

    // ---- dispatch 2: cooperative mega ----
    MegaP p;
    p.src = src; p.dst = dst; p.n_edges = n_edges; p.n_nodes = n_nodes; p.nbt = nbt;
    p.cnt = cnt; p.row_ptr = row_ptr; p.woff = woff; p.bsums = bsums;
    p.src_sorted = src_sorted; p.xh = xh; p.agg = agg;
    p.whi = whi; p.wlo = wlo;
    p.b1 = b1; p.b2 = b2; p.b3 = b3; p.b4 = b4;
    p.x4 = x4; p.Wl = Wl; p.bl = bl; p.logits = logits; p.probs = probs;

    int maxPerCU = 0;
    hipOccupancyMaxActiveBlocksPerMultiprocessor(&maxPerCU, mega_kernel, 256, 0);
    if (maxPerCU < 1) maxPerCU = 1;
    int grid = maxPerCU * NCU;
    if (grid > 1024) grid = 1024;
    void* kargs[] = { (void*)&p };
    hipLaunchCooperativeKernel((const void*)mega_kernel, dim3(grid), dim3(256),
                               kargs, 0, stream);
}

// Round 9
// 376.254 us; speedup vs baseline: 3.6807x; 3.6807x over previous
//
#include <hip/hip_runtime.h>
#include <hip/hip_bf16.h>
#include <hip/hip_fp16.h>
#include <math.h>

#define NFEAT 128
#define NCLASS 40

typedef __attribute__((ext_vector_type(8))) short frag_ab;   // 8 bf16 (4 VGPRs)
typedef __attribute__((ext_vector_type(4))) float frag_cd;   // 4 fp32 acc

static __device__ inline unsigned short f2bf_rne(float f) {
    union { float f; unsigned u; } v;
    v.f = f;
    unsigned r = v.u + 0x7FFFu + ((v.u >> 16) & 1u);  // round-to-nearest-even
    return (unsigned short)(r >> 16);
}
static __device__ inline float bf2f(unsigned short h) {
    union { unsigned u; float f; } v;
    v.u = ((unsigned)h) << 16;
    return v.f;
}

// ---------------- prep: conv(x->fp16) + zero(cnt) + wprep, by block range ----------------
// (ran correctly inside R7's passing run)

__global__ __launch_bounds__(256) void prep_kernel(const float* __restrict__ x,
                                                   __half* __restrict__ xh, int xc4,
                                                   int* __restrict__ cnt, int n_nodes,
                                                   const float* __restrict__ W0,
                                                   const float* __restrict__ W1,
                                                   const float* __restrict__ W2,
                                                   const float* __restrict__ W3,
                                                   short* __restrict__ whi,
                                                   short* __restrict__ wlo,
                                                   int convB, int zeroB) {
    int b = blockIdx.x;
    if (b < convB) {
        int i = b * 256 + threadIdx.x;
        if (i < xc4) {
            float4 v = ((const float4*)x)[i];
            ((__half2*)xh)[i * 2 + 0] = __floats2half2_rn(v.x, v.y);
            ((__half2*)xh)[i * 2 + 1] = __floats2half2_rn(v.z, v.w);
        }
    } else if (b < convB + zeroB) {
        int i = (b - convB) * 256 + threadIdx.x;
        if (i < n_nodes) cnt[i] = 0;
    } else {
        int wb = b - convB - zeroB;        // 0..31
        int layer = wb >> 3;               // 8 blocks per layer
        const float* W = layer == 0 ? W0 : layer == 1 ? W1 : layer == 2 ? W2 : W3;
        short* h = whi + (size_t)layer * 16384;
        short* l = wlo + (size_t)layer * 16384;
        int idx = (wb & 7) * 256 + threadIdx.x;  // frag slot 0..2047
        int lane = idx & 63;
        int t = (idx >> 6) & 7;
        int s = idx >> 9;
        int quad = lane >> 4;
        int n = lane & 15;
        int kbase = s * 32 + quad * 8;
        int col = t * 16 + n;
#pragma unroll
        for (int j = 0; j < 8; ++j) {
            float f = W[(size_t)(kbase + j) * NFEAT + col];
            unsigned short hb = f2bf_rne(f);
            unsigned short lb = f2bf_rne(f - bf2f(hb));
            h[(size_t)idx * 8 + j] = (short)hb;
            l[(size_t)idx * 8 + j] = (short)lb;
        }
    }
}

// ---------------- CSR build (R6 proven) ----------------

__global__ __launch_bounds__(256) void hist_kernel(const int* __restrict__ dst,
                                                   int* __restrict__ counts, int n_edges) {
    int i = blockIdx.x * 256 + threadIdx.x;
    int n4 = n_edges >> 2;
    if (i < n4) {
        int4 d = ((const int4*)dst)[i];
        atomicAdd(&counts[d.x], 1);
        atomicAdd(&counts[d.y], 1);
        atomicAdd(&counts[d.z], 1);
        atomicAdd(&counts[d.w], 1);
    }
    if (i == 0) {
        for (int e = n4 << 2; e < n_edges; ++e) atomicAdd(&counts[dst[e]], 1);
    }
}

__global__ __launch_bounds__(256) void scan1_kernel(const int* __restrict__ cnt,
                                                    int* __restrict__ excl,
                                                    int* __restrict__ bsums, int n) {
    __shared__ int sd[256];
    int t = threadIdx.x;
    int i = blockIdx.x * 256 + t;
    int v = (i < n) ? cnt[i] : 0;
    sd[t] = v;
    __syncthreads();
#pragma unroll
    for (int off = 1; off < 256; off <<= 1) {
        int tmp = (t >= off) ? sd[t - off] : 0;
        __syncthreads();
        sd[t] += tmp;
        __syncthreads();
    }
    if (i < n) excl[i] = sd[t] - v;
    if (t == 255) bsums[blockIdx.x] = sd[255];
}

__global__ __launch_bounds__(256) void scan2_kernel(int* __restrict__ bsums, int nb) {
    __shared__ int sd[256];
    int t = threadIdx.x;
    int v = (t < nb) ? bsums[t] : 0;
    sd[t] = v;
    __syncthreads();
#pragma unroll
    for (int off = 1; off < 256; off <<= 1) {
        int tmp = (t >= off) ? sd[t - off] : 0;
        __syncthreads();
        sd[t] += tmp;
        __syncthreads();
    }
    if (t < nb) bsums[t] = sd[t] - v;
    if (t == 255) bsums[nb] = sd[255];
}

__global__ __launch_bounds__(256) void scan3_kernel(const int* __restrict__ excl,
                                                    const int* __restrict__ bsums,
                                                    int* __restrict__ row_ptr,
                                                    int* __restrict__ woff, int n, int nb) {
    int i = blockIdx.x * 256 + threadIdx.x;
    if (i < n) {
        int v = excl[i] + bsums[blockIdx.x];
        row_ptr[i] = v;
        woff[i] = v;
    }
    if (i == 0) row_ptr[n] = bsums[nb];
}

__global__ __launch_bounds__(256) void scatter_kernel(const int* __restrict__ src,
                                                      const int* __restrict__ dst,
                                                      int* __restrict__ woff,
                                                      int* __restrict__ src_sorted, int n_edges) {
    int i = blockIdx.x * 256 + threadIdx.x;
    int n4 = n_edges >> 2;
    if (i < n4) {
        int4 d = ((const int4*)dst)[i];
        int4 s = ((const int4*)src)[i];
        int p0 = atomicAdd(&woff[d.x], 1);
        int p1 = atomicAdd(&woff[d.y], 1);
        int p2 = atomicAdd(&woff[d.z], 1);
        int p3 = atomicAdd(&woff[d.w], 1);
        src_sorted[p0] = s.x;
        src_sorted[p1] = s.y;
        src_sorted[p2] = s.z;
        src_sorted[p3] = s.w;
    }
    if (i == 0) {
        for (int e = n4 << 2; e < n_edges; ++e) {
            int p = atomicAdd(&woff[dst[e]], 1);
            src_sorted[p] = src[e];
        }
    }
}

// ---------------- aggregation over fp16 features -> fp16 agg ----------------
// Quarter-wave (16 lanes x 16 B) per node; 4-deep gather pipeline (R6 proven).
// fp32 accumulate, single fp16 rounding on output (halves agg write+read bytes).

__global__ __launch_bounds__(256) void agg_h_kernel(const __half* __restrict__ xin,
                                                    const int* __restrict__ row_ptr,
                                                    const int* __restrict__ src_sorted,
                                                    __half* __restrict__ aggh, int n_nodes) {
    int node = blockIdx.x * 16 + (threadIdx.x >> 4);
    if (node >= n_nodes) return;
    int c = threadIdx.x & 15;  // 16B group: cols [8c, 8c+8)
    int jb = row_ptr[node], je = row_ptr[node + 1];
    const uint4* xp = (const uint4*)xin;  // fp16 row = 16 uint4

    float a[8];
#pragma unroll
    for (int i = 0; i < 8; ++i) a[i] = 0.f;

    int j = jb;
    for (; j + 3 < je; j += 4) {
        int s0 = src_sorted[j];
        int s1 = src_sorted[j + 1];
        int s2 = src_sorted[j + 2];
        int s3 = src_sorted[j + 3];
        uint4 r0 = xp[s0 * 16 + c];
        uint4 r1 = xp[s1 * 16 + c];
        uint4 r2 = xp[s2 * 16 + c];
        uint4 r3 = xp[s3 * 16 + c];
#pragma unroll
        for (int q = 0; q < 4; ++q) {
            unsigned u0 = (&r0.x)[q], u1 = (&r1.x)[q], u2 = (&r2.x)[q], u3 = (&r3.x)[q];
            float2 f0 = __half22float2(*(__half2*)&u0);
            float2 f1 = __half22float2(*(__half2*)&u1);
            float2 f2 = __half22float2(*(__half2*)&u2);
            float2 f3 = __half22float2(*(__half2*)&u3);
            a[q * 2 + 0] += f0.x + f1.x + f2.x + f3.x;
            a[q * 2 + 1] += f0.y + f1.y + f2.y + f3.y;
        }
    }
    for (; j < je; ++j) {
        int s0 = src_sorted[j];
        uint4 r0 = xp[s0 * 16 + c];
#pragma unroll
        for (int q = 0; q < 4; ++q) {
            unsigned u0 = (&r0.x)[q];
            float2 f0 = __half22float2(*(__half2*)&u0);
            a[q * 2 + 0] += f0.x;
            a[q * 2 + 1] += f0.y;
        }
    }
    __half2 h0 = __floats2half2_rn(a[0], a[1]);
    __half2 h1 = __floats2half2_rn(a[2], a[3]);
    __half2 h2 = __floats2half2_rn(a[4], a[5]);
    __half2 h3 = __floats2half2_rn(a[6], a[7]);
    uint4 o;
    o.x = *(unsigned*)&h0; o.y = *(unsigned*)&h1; o.z = *(unsigned*)&h2; o.w = *(unsigned*)&h3;
    ((uint4*)aggh)[(size_t)node * 16 + c] = o;
}

// ---------------- MFMA GEMM (fp16 A) + bias + L2-normalize + ReLU ----------------
// Split-bf16 (hi*hi + hi*lo + lo*hi), fp32 acc. fp16 -> bf16 hi+lo split is
// EXACT (11-bit mantissa fits 8+residual), so no error beyond agg's fp16 round.

__global__ __launch_bounds__(256) void gemm_mfma_kernel(const __half* __restrict__ A,
                                                        const short* __restrict__ whi,
                                                        const short* __restrict__ wlo,
                                                        const float* __restrict__ bias,
                                                        float* __restrict__ outf,
                                                        __half* __restrict__ outh, int M) {
    int tid = threadIdx.x;
    int wave = tid >> 6;
    int lane = tid & 63;
    int quad = lane >> 4;
    int n16 = lane & 15;
    int base = blockIdx.x * 64;

    int arow = base + wave * 16 + n16;
    int arc = arow < M ? arow : M - 1;
    const __half* Ar = A + (size_t)arc * NFEAT;

    const frag_ab* WH = (const frag_ab*)whi;
    const frag_ab* WL = (const frag_ab*)wlo;

    frag_cd acc[8];
#pragma unroll
    for (int t = 0; t < 8; ++t) acc[t] = (frag_cd){0.f, 0.f, 0.f, 0.f};

#pragma unroll
    for (int s = 0; s < 4; ++s) {
        uint4 av = *(const uint4*)(Ar + s * 32 + quad * 8);  // 8 halfs, 16 B
        frag_ab ah, al;
#pragma unroll
        for (int q = 0; q < 4; ++q) {
            unsigned u = (&av.x)[q];
            float2 f = __half22float2(*(__half2*)&u);
            unsigned short hb0 = f2bf_rne(f.x);
            unsigned short hb1 = f2bf_rne(f.y);
            ah[q * 2 + 0] = (short)hb0;
            ah[q * 2 + 1] = (short)hb1;
            al[q * 2 + 0] = (short)f2bf_rne(f.x - bf2f(hb0));
            al[q * 2 + 1] = (short)f2bf_rne(f.y - bf2f(hb1));
        }
#pragma unroll
        for (int t = 0; t < 8; ++t) {
            frag_ab bh = WH[(s * 8 + t) * 64 + lane];
            frag_ab bl = WL[(s * 8 + t) * 64 + lane];
            acc[t] = __builtin_amdgcn_mfma_f32_16x16x32_bf16(ah, bh, acc[t], 0, 0, 0);
            acc[t] = __builtin_amdgcn_mfma_f32_16x16x32_bf16(ah, bl, acc[t], 0, 0, 0);
            acc[t] = __builtin_amdgcn_mfma_f32_16x16x32_bf16(al, bh, acc[t], 0, 0, 0);
        }
    }

    // epilogue: bias -> row sum-of-squares -> normalize -> relu -> store
    float ssq[4] = {0.f, 0.f, 0.f, 0.f};
#pragma unroll
    for (int t = 0; t < 8; ++t) {
        float bv = bias[t * 16 + n16];
#pragma unroll
        for (int r = 0; r < 4; ++r) {
            acc[t][r] += bv;
            ssq[r] += acc[t][r] * acc[t][r];
        }
    }
#pragma unroll
    for (int mask = 1; mask <= 8; mask <<= 1) {
#pragma unroll
        for (int r = 0; r < 4; ++r) ssq[r] += __shfl_xor(ssq[r], mask);
    }
    float inv[4];
#pragma unroll
    for (int r = 0; r < 4; ++r) inv[r] = 1.0f / fmaxf(sqrtf(ssq[r]), 1e-12f);

    int orow0 = base + wave * 16 + quad * 4;
#pragma unroll
    for (int r = 0; r < 4; ++r) {
        int orow = orow0 + r;
        if (orow < M) {
            if (outh) {
                __half* op = outh + (size_t)orow * NFEAT + n16;
#pragma unroll
                for (int t = 0; t < 8; ++t)
                    op[t * 16] = __float2half(fmaxf(acc[t][r] * inv[r], 0.f));
            } else {
                float* op = outf + (size_t)orow * NFEAT + n16;
#pragma unroll
                for (int t = 0; t < 8; ++t)
                    op[t * 16] = fmaxf(acc[t][r] * inv[r], 0.f);
            }
        }
    }
}

// ---------------- classifier: logits = x4 @ Wl + bl; softmax (R2 proven) ----------------

__global__ __launch_bounds__(256) void classifier_kernel(const float* __restrict__ x4,
                                                         const float* __restrict__ Wl,
                                                         const float* __restrict__ bl,
                                                         float* __restrict__ logits,
                                                         float* __restrict__ probs, int n_nodes) {
    int node = blockIdx.x * 256 + threadIdx.x;
    int nc = node < n_nodes ? node : n_nodes - 1;
    const float* row = x4 + (size_t)nc * NFEAT;

    float acc[NCLASS];
#pragma unroll
    for (int c = 0; c < NCLASS; ++c) acc[c] = bl[c];

    for (int k = 0; k < NFEAT; k += 4) {
        float4 a = *(const float4*)(row + k);
#pragma unroll
        for (int kk = 0; kk < 4; ++kk) {
            float av = (&a.x)[kk];
            const float* Wr = Wl + (k + kk) * NCLASS;
#pragma unroll
            for (int c = 0; c < NCLASS; ++c) acc[c] += av * Wr[c];
        }
    }

    float m = acc[0];
#pragma unroll
    for (int c = 1; c < NCLASS; ++c) m = fmaxf(m, acc[c]);
    float ex[NCLASS];
    float sum = 0.f;
#pragma unroll
    for (int c = 0; c < NCLASS; ++c) {
        ex[c] = __expf(acc[c] - m);
        sum += ex[c];
    }
    float is = 1.0f / sum;

    if (node < n_nodes) {
        float4* lo = (float4*)(logits + (size_t)node * NCLASS);
        float4* po = (float4*)(probs + (size_t)node * NCLASS);
#pragma unroll
        for (int c = 0; c < NCLASS; c += 4) {
            float4 lv, pv;
            lv.x = acc[c + 0]; lv.y = acc[c + 1]; lv.z = acc[c + 2]; lv.w = acc[c + 3];
            pv.x = ex[c + 0] * is; pv.y = ex[c + 1] * is; pv.z = ex[c + 2] * is; pv.w = ex[c + 3] * is;
            lo[c >> 2] = lv;
            po[c >> 2] = pv;
        }
    }
}

// ---------------- launch ----------------

extern "C" void kernel_launch(void* const* d_in, const int* in_sizes, int n_in,
                              void* d_out, int out_size, void* d_ws, size_t ws_size,
                              hipStream_t stream) {
    const float* x  = (const float*)d_in[0];
    const int*   ei = (const int*)d_in[1];
    const float* W1 = (const float*)d_in[2];
    const float* b1 = (const float*)d_in[3];
    const float* W2 = (const float*)d_in[4];
    const float* b2 = (const float*)d_in[5];
    const float* W3 = (const float*)d_in[6];
    const float* b3 = (const float*)d_in[7];
    const float* W4 = (const float*)d_in[8];
    const float* b4 = (const float*)d_in[9];
    const float* Wl = (const float*)d_in[10];
    const float* bl = (const float*)d_in[11];

    const int n_nodes = in_sizes[0] / NFEAT;  // 50000
    const int n_edges = in_sizes[1] / 2;      // 640000
    const int* src = ei;
    const int* dst = ei + n_edges;

    float* out    = (float*)d_out;
    float* logits = out;
    float* probs  = out + (size_t)n_nodes * NCLASS;
    float* x4     = out + 2 * (size_t)n_nodes * NCLASS;  // final fp32 features

    char* ws = (char*)d_ws;
    size_t off = 0;
    auto wsalloc = [&](size_t bytes) -> void* {
        void* p = ws + off;
        off += (bytes + 255) & ~(size_t)255;
        return p;
    };
    __half* aggh       = (__half*)wsalloc((size_t)n_nodes * NFEAT * sizeof(__half));
    __half* xh         = (__half*)wsalloc((size_t)n_nodes * NFEAT * sizeof(__half));
    int*    row_ptr    = (int*)wsalloc(((size_t)n_nodes + 1) * sizeof(int));
    int*    woff       = (int*)wsalloc((size_t)n_nodes * sizeof(int));
    int*    cnt        = (int*)wsalloc((size_t)n_nodes * sizeof(int));
    int*    src_sorted = (int*)wsalloc((size_t)n_edges * sizeof(int));
    int     nbt        = (n_nodes + 255) / 256;
    int*    bsums      = (int*)wsalloc(((size_t)nbt + 1) * sizeof(int));
    short*  whi        = (short*)wsalloc((size_t)4 * 16384 * sizeof(short));
    short*  wlo        = (short*)wsalloc((size_t)4 * 16384 * sizeof(short));

    // dispatch 1: prep (conv + zero cnt + wprep)
    int xc4   = (n_nodes * NFEAT) / 4;
    int convB = (xc4 + 255) / 256;
    int zeroB = (n_nodes + 255) / 256;
    prep_kernel<<<convB + zeroB + 32, 256, 0, stream>>>(x, xh, xc4, cnt, n_nodes,
                                                        W1, W2, W3, W4, whi, wlo,
                                                        convB, zeroB);

    // CSR build (dst-bucketed)
    int e4b = ((n_edges >> 2) + 255) / 256;
    hist_kernel<<<e4b, 256, 0, stream>>>(dst, cnt, n_edges);
    scan1_kernel<<<nbt, 256, 0, stream>>>(cnt, row_ptr /*excl temp*/, bsums, n_nodes);
    scan2_kernel<<<1, 256, 0, stream>>>(bsums, nbt);
    scan3_kernel<<<nbt, 256, 0, stream>>>(row_ptr, bsums, row_ptr, woff, n_nodes, nbt);
    scatter_kernel<<<e4b, 256, 0, stream>>>(src, dst, woff, src_sorted, n_edges);

    int ah = (n_nodes + 15) / 16;
    int gb = (n_nodes + 63) / 64;
    int cb = (n_nodes + 255) / 256;

    // fused layers (agg-first reordering; xh ping buffer fully consumed each layer)
    agg_h_kernel<<<ah, 256, 0, stream>>>(xh, row_ptr, src_sorted, aggh, n_nodes);
    gemm_mfma_kernel<<<gb, 256, 0, stream>>>(aggh, whi + 0 * 16384, wlo + 0 * 16384, b1, nullptr, xh, n_nodes);
    agg_h_kernel<<<ah, 256, 0, stream>>>(xh, row_ptr, src_sorted, aggh, n_nodes);
    gemm_mfma_kernel<<<gb, 256, 0, stream>>>(aggh, whi + 1 * 16384, wlo + 1 * 16384, b2, nullptr, xh, n_nodes);
    agg_h_kernel<<<ah, 256, 0, stream>>>(xh, row_ptr, src_sorted, aggh, n_nodes);
    gemm_mfma_kernel<<<gb, 256, 0, stream>>>(aggh, whi + 2 * 16384, wlo + 2 * 16384, b3, nullptr, xh, n_nodes);
    agg_h_kernel<<<ah, 256, 0, stream>>>(xh, row_ptr, src_sorted, aggh, n_nodes);
    gemm_mfma_kernel<<<gb, 256, 0, stream>>>(aggh, whi + 3 * 16384, wlo + 3 * 16384, b4, x4, nullptr, n_nodes);

    // classifier + softmax
    classifier_kernel<<<cb, 256, 0, stream>>>(x4, Wl, bl, logits, probs, n_nodes);
}